// Round 15
// baseline (566.747 us; speedup 1.0000x reference)
//
#include <hip/hip_runtime.h>
#include <hip/hip_bf16.h>
#include <cstddef>

#define BB 2
#define HH 64
#define WW 64
#define SCALE 0.17677669529663687f   // 32^-0.5

// natten tile geometry: 4x8 queries per block
#define HALO_H 10
#define HALO_W 14
#define NPIX 140
#define NQ 32

// measurement amplification (kernels idempotent; cost = amplified_dur / REP)
#define REP_K1 16
#define REP_K2 8

typedef short short8 __attribute__((ext_vector_type(8)));
typedef float f32x4 __attribute__((ext_vector_type(4)));

#if defined(__has_builtin)
#if __has_builtin(__builtin_amdgcn_fdot2_f32_bf16)
#define HAS_BFDOT2 1
#endif
#endif
#ifndef HAS_BFDOT2
#define HAS_BFDOT2 0
#endif

#if HAS_BFDOT2
typedef __bf16 v2bf __attribute__((ext_vector_type(2)));
__device__ inline float bfdot2(uint a, uint b, float c) {
    union { uint u; v2bf v; } ua, ub;
    ua.u = a; ub.u = b;
    return __builtin_amdgcn_fdot2_f32_bf16(ua.v, ub.v, c, false);
}
#endif

__device__ inline ushort f2bf(float f) {
    union { __hip_bfloat16 b; ushort u; } cv;
    cv.b = __float2bfloat16(f);
    return cv.u;
}
__device__ inline float bflo(uint u) { union { uint i; float f; } c; c.i = u << 16; return c.f; }
__device__ inline float bfhi(uint u) { union { uint i; float f; } c; c.i = u & 0xffff0000u; return c.f; }

// ---------------------------------------------------------------------------
// K1: qkv GEMM (R13 proven), amplified x REP_K1 for measurement.
// ---------------------------------------------------------------------------
__global__ __launch_bounds__(256) void qkv_gemm_fused_kernel(
    const float* __restrict__ x, const float* __restrict__ w_qkv,
    const float* __restrict__ b_qkv, const float* __restrict__ w_proj,
    ushort* __restrict__ qkv, ushort* __restrict__ Wp_t)
{
    __shared__ ushort S[64 * 128 + 96 * 128];   // As | Bs  (40KB)
    ushort* As = S;
    ushort* Bs = S + 64 * 128;

    const int tid = threadIdx.x;
    const int m0 = blockIdx.x * 64;
    const int n0 = blockIdx.y * 96;

    for (int rep = 0; rep < REP_K1; ++rep) {
    if (blockIdx.y == 0 && tid < 128)
        Wp_t[(size_t)blockIdx.x * 128 + tid] =
            f2bf(w_proj[(size_t)tid * 128 + blockIdx.x]);

    #pragma unroll
    for (int t = 0; t < 4; ++t) {
        int idx = tid + t * 256;
        int r = idx >> 4, c = idx & 15;
        const float* src = x + (size_t)(m0 + r) * 128 + c * 8;
        float4 v0 = *(const float4*)src;
        float4 v1 = *(const float4*)(src + 4);
        union { ushort s[8]; uint4 q; } u;
        u.s[0] = f2bf(v0.x); u.s[1] = f2bf(v0.y); u.s[2] = f2bf(v0.z); u.s[3] = f2bf(v0.w);
        u.s[4] = f2bf(v1.x); u.s[5] = f2bf(v1.y); u.s[6] = f2bf(v1.z); u.s[7] = f2bf(v1.w);
        *(uint4*)&As[r * 128 + (c ^ (r & 7)) * 8] = u.q;
    }
    #pragma unroll
    for (int t = 0; t < 6; ++t) {
        int idx = tid + t * 256;
        int kc = idx / 96, n = idx - kc * 96;
        union { ushort s[8]; uint4 q; } u;
        #pragma unroll
        for (int e = 0; e < 8; ++e)
            u.s[e] = f2bf(w_qkv[(size_t)(kc * 8 + e) * 384 + n0 + n]);
        *(uint4*)&Bs[n * 128 + ((kc ^ (n & 7)) * 8)] = u.q;
    }
    __syncthreads();

    const int wid = tid >> 6, lane = tid & 63;
    const int l15 = lane & 15, l4 = lane >> 4;
    const int mr = (wid >> 1) * 32, nr = (wid & 1) * 48;

    f32x4 acc[2][3] = {};
    #pragma unroll
    for (int ks = 0; ks < 4; ++ks) {
        short8 af[2], bf[3];
        #pragma unroll
        for (int fm = 0; fm < 2; ++fm) {
            int row = mr + fm * 16 + l15;
            af[fm] = *(const short8*)&As[row * 128 + ((ks * 4 + l4) ^ (row & 7)) * 8];
        }
        #pragma unroll
        for (int fn = 0; fn < 3; ++fn) {
            int row = nr + fn * 16 + l15;
            bf[fn] = *(const short8*)&Bs[row * 128 + ((ks * 4 + l4) ^ (row & 7)) * 8];
        }
        #pragma unroll
        for (int fm = 0; fm < 2; ++fm)
            #pragma unroll
            for (int fn = 0; fn < 3; ++fn)
                acc[fm][fn] = __builtin_amdgcn_mfma_f32_16x16x32_bf16(
                    af[fm], bf[fn], acc[fm][fn], 0, 0, 0);
    }

    __syncthreads();
    ushort* C_s = S;                      // 64 x 200 overlay
    #pragma unroll
    for (int fn = 0; fn < 3; ++fn) {
        int colb = nr + fn * 16;
        int col = colb + l15;
        float bc = b_qkv[n0 + col];
        float sc = (n0 + colb < 128) ? SCALE : 1.0f;
        #pragma unroll
        for (int fm = 0; fm < 2; ++fm)
            #pragma unroll
            for (int reg = 0; reg < 4; ++reg) {
                int row = mr + fm * 16 + l4 * 4 + reg;
                C_s[row * 200 + col] = f2bf((acc[fm][fn][reg] + bc) * sc);
            }
    }
    __syncthreads();
    #pragma unroll
    for (int t = 0; t < 3; ++t) {
        int idx = tid + t * 256;
        int row = idx / 12, c = idx - row * 12;
        uint4 v = *(const uint4*)&C_s[row * 200 + c * 8];
        *(uint4*)&qkv[(size_t)(m0 + row) * 384 + n0 + c * 8] = v;
    }
    __syncthreads();   // rep boundary: C_s reads done before next staging
    }
}

// ---------------------------------------------------------------------------
// K2: wave-per-head fused natten + proj (R14), amplified x REP_K2.
// ---------------------------------------------------------------------------
__global__ __launch_bounds__(256) void natten_proj_kernel(
    const ushort* __restrict__ qkv,     // (B*H*W) x 384 bf16, q pre-scaled
    const float* __restrict__ rpb,      // 4 x 13 x 13
    const ushort* __restrict__ Wp_t,    // 128 x 128 bf16, [n][k]
    const float* __restrict__ b_proj,   // 128
    float* __restrict__ out)            // (B*H*W) x 128 f32
{
    __shared__ ushort KV_s[4][NPIX * 64];  // 71.7KB
    __shared__ ushort AO_s[NQ * 128];      // 8KB
    __shared__ float rpb_s[676];           // 2.7KB

    const int tid = threadIdx.x;
    const int wv = tid >> 6;               // wave = head
    const int lane = tid & 63;
    const int bx = ((blockIdx.x & 7) << 5) | (blockIdx.x >> 3);
    const int b  = bx >> 7;
    const int th = (bx >> 3) & 15;
    const int tw = bx & 7;
    const int h0 = th * 4, w0 = tw * 8;
    const int ho = max(0, h0 - 3), wo = max(0, w0 - 3);

    const int q = lane >> 1, half = lane & 1;
    const int qh = h0 + (q >> 3), qw = w0 + (q & 7);
    const int hs = min(max(qh - 3, 0), HH - 7);
    const int ws = min(max(qw - 3, 0), WW - 7);
    const int base_lp = (hs - ho) * HALO_W + (ws - wo);
    const int bh0 = hs - qh + 6, bw0 = ws - qw + 6;
    const size_t qpix = (size_t)((b << 12) + (qh << 6) + qw);

    for (int rep = 0; rep < REP_K2; ++rep) {
    #pragma unroll
    for (int t = 0; t < 3; ++t) {
        int idx = tid + t * 256;
        if (idx < 676) rpb_s[idx] = rpb[idx];
    }

    ushort* KV = &KV_s[wv][0];
    #pragma unroll
    for (int t = 0; t < 18; ++t) {
        int idx = lane + t * 64;
        if (idx < NPIX * 8) {
            int pix = idx >> 3, s = idx & 7;
            int r = pix / HALO_W, c = pix - r * HALO_W;
            int gh = min(ho + r, HH - 1), gw = min(wo + c, WW - 1);
            const ushort* gp = qkv + (size_t)((b << 12) + (gh << 6) + gw) * 384
                               + 128 + (s >> 2) * 128 + wv * 32 + (s & 3) * 8;
            uint4 v = *(const uint4*)gp;
            int bb = (pix >> 2) & 1;
            int slot = (2 * ((s & 3) ^ (pix & 3)) ^ bb) ^ (s >> 2);
            *(uint4*)&KV[pix * 64 + slot * 8] = v;
        }
    }

#if HAS_BFDOT2
    uint4 qb[4];
    #pragma unroll
    for (int d4 = 0; d4 < 4; ++d4)
        qb[d4] = *(const uint4*)(qkv + qpix * 384 + wv * 32 + d4 * 8);
#else
    float qf[32];
    #pragma unroll
    for (int d4 = 0; d4 < 4; ++d4) {
        uint4 qu = *(const uint4*)(qkv + qpix * 384 + wv * 32 + d4 * 8);
        qf[d4*8+0] = bflo(qu.x); qf[d4*8+1] = bfhi(qu.x);
        qf[d4*8+2] = bflo(qu.y); qf[d4*8+3] = bfhi(qu.y);
        qf[d4*8+4] = bflo(qu.z); qf[d4*8+5] = bfhi(qu.z);
        qf[d4*8+6] = bflo(qu.w); qf[d4*8+7] = bfhi(qu.w);
    }
#endif
    __syncthreads();   // barrier 1: all KV quadrants staged

    float lg[25];
    #pragma unroll
    for (int i = 0; i < 25; ++i) {
        int j = half + 2 * i;
        float s = -1e30f;
        if (j < 49) {
            int p = (j * 37) >> 8;            // exact j/7 for j<=48
            int qq = j - p * 7;
            int lp = base_lp + p * HALO_W + qq;
            int bb = (lp >> 2) & 1;
            float a = 0.f;
            #pragma unroll
            for (int d4 = 0; d4 < 4; ++d4) {
                uint4 ku = *(const uint4*)&KV[lp * 64 + ((2 * (d4 ^ (lp & 3)) ^ bb) * 8)];
#if HAS_BFDOT2
                a = bfdot2(ku.x, qb[d4].x, a);
                a = bfdot2(ku.y, qb[d4].y, a);
                a = bfdot2(ku.z, qb[d4].z, a);
                a = bfdot2(ku.w, qb[d4].w, a);
#else
                a += bflo(ku.x)*qf[d4*8+0] + bfhi(ku.x)*qf[d4*8+1]
                   + bflo(ku.y)*qf[d4*8+2] + bfhi(ku.y)*qf[d4*8+3]
                   + bflo(ku.z)*qf[d4*8+4] + bfhi(ku.z)*qf[d4*8+5]
                   + bflo(ku.w)*qf[d4*8+6] + bfhi(ku.w)*qf[d4*8+7];
#endif
            }
            s = a + rpb_s[wv * 169 + (bh0 + p) * 13 + (bw0 + qq)];
        }
        lg[i] = s;
    }

    float m = lg[0];
    #pragma unroll
    for (int i = 1; i < 25; ++i) m = fmaxf(m, lg[i]);
    m = fmaxf(m, __shfl_xor(m, 1));
    float ssum = 0.f;
    #pragma unroll
    for (int i = 0; i < 25; ++i) {
        int j = half + 2 * i;
        lg[i] = (j < 49) ? __expf(lg[i] - m) : 0.f;
        ssum += lg[i];
    }
    ssum += __shfl_xor(ssum, 1);
    float inv = 1.f / ssum;
    #pragma unroll
    for (int i = 0; i < 25; ++i) lg[i] *= inv;

    float o[32] = {};
    #pragma unroll
    for (int i = 0; i < 25; ++i) {
        int j = half + 2 * i;
        if (j < 49) {
            int p = (j * 37) >> 8;
            int qq = j - p * 7;
            int lp = base_lp + p * HALO_W + qq;
            int bb = (lp >> 2) & 1;
            float a = lg[i];
            #pragma unroll
            for (int d4 = 0; d4 < 4; ++d4) {
                uint4 vu = *(const uint4*)&KV[lp * 64 + (((2 * (d4 ^ (lp & 3)) ^ bb) ^ 1) * 8)];
                o[d4*8+0] += a * bflo(vu.x); o[d4*8+1] += a * bfhi(vu.x);
                o[d4*8+2] += a * bflo(vu.y); o[d4*8+3] += a * bfhi(vu.y);
                o[d4*8+4] += a * bflo(vu.z); o[d4*8+5] += a * bfhi(vu.z);
                o[d4*8+6] += a * bflo(vu.w); o[d4*8+7] += a * bfhi(vu.w);
            }
        }
    }
    #pragma unroll
    for (int e = 0; e < 32; ++e) o[e] += __shfl_xor(o[e], 1);

    #pragma unroll
    for (int cc = 0; cc < 2; ++cc) {
        int d4 = half * 2 + cc;
        union { ushort s[8]; uint4 u4; } w;
        #pragma unroll
        for (int e = 0; e < 8; ++e) w.s[e] = f2bf(o[d4 * 8 + e]);
        *(uint4*)&AO_s[q * 128 + (((wv * 4 + d4) ^ (q & 7)) * 8)] = w.u4;
    }
    __syncthreads();   // barrier 2: AO complete

    const int l15 = lane & 15, l4 = lane >> 4;
    const int wr = wv >> 1, wc = wv & 1;

    f32x4 pacc[4] = {};
    #pragma unroll
    for (int ks = 0; ks < 4; ++ks) {
        int arow = wr * 16 + l15;
        short8 af = *(const short8*)&AO_s[arow * 128 + ((ks * 4 + l4) ^ (arow & 7)) * 8];
        #pragma unroll
        for (int fn = 0; fn < 4; ++fn) {
            int brow = wc * 64 + fn * 16 + l15;
            short8 bf = *(const short8*)(Wp_t + (size_t)brow * 128 + (ks * 4 + l4) * 8);
            pacc[fn] = __builtin_amdgcn_mfma_f32_16x16x32_bf16(af, bf, pacc[fn], 0, 0, 0);
        }
    }
    #pragma unroll
    for (int fn = 0; fn < 4; ++fn) {
        int col = wc * 64 + fn * 16 + l15;
        float bc = b_proj[col];
        #pragma unroll
        for (int reg = 0; reg < 4; ++reg) {
            int q2 = wr * 16 + l4 * 4 + reg;
            int oh = h0 + (q2 >> 3), ow = w0 + (q2 & 7);
            out[(size_t)((b << 12) + (oh << 6) + ow) * 128 + col] = pacc[fn][reg] + bc;
        }
    }
    __syncthreads();   // rep boundary: AO_s reads done before next rep
    }
}

extern "C" void kernel_launch(void* const* d_in, const int* in_sizes, int n_in,
                              void* d_out, int out_size, void* d_ws, size_t ws_size,
                              hipStream_t stream)
{
    const float* x      = (const float*)d_in[0];
    const float* w_qkv  = (const float*)d_in[1];
    const float* b_qkv  = (const float*)d_in[2];
    const float* rpb    = (const float*)d_in[3];
    const float* w_proj = (const float*)d_in[4];
    const float* b_proj = (const float*)d_in[5];
    float* out = (float*)d_out;

    const int M = BB * HH * WW;                   // 8192
    ushort* qkv  = (ushort*)d_ws;                 // M x 384 bf16
    ushort* Wp_t = qkv + (size_t)M * 384;         // 128 x 128 bf16

    // MEASUREMENT ROUND 3: amplified 2-kernel pipeline. Per-kernel cost =
    // amplified dispatch dur / REP; both dispatches surface in top-5 with
    // full counters (they exceed the ~43us reset fills).
    qkv_gemm_fused_kernel<<<dim3(128, 4), 256, 0, stream>>>(
        x, w_qkv, b_qkv, w_proj, qkv, Wp_t);

    natten_proj_kernel<<<256, 256, 0, stream>>>(
        qkv, rpb, Wp_t, b_proj, out);
}

// Round 16
// 49.083 us; speedup vs baseline: 11.5467x; 11.5467x over previous
//
#include <hip/hip_runtime.h>
#include <hip/hip_bf16.h>
#include <cstddef>

#define BB 2
#define HH 64
#define WW 64
#define SCALE 0.17677669529663687f   // 32^-0.5

// natten tile geometry: 4x8 queries per block
#define HALO_H 10
#define HALO_W 14
#define NPIX 140
#define NQ 32

typedef short short8 __attribute__((ext_vector_type(8)));
typedef float f32x4 __attribute__((ext_vector_type(4)));

#if defined(__has_builtin)
#if __has_builtin(__builtin_amdgcn_fdot2_f32_bf16)
#define HAS_BFDOT2 1
#endif
#endif
#ifndef HAS_BFDOT2
#define HAS_BFDOT2 0
#endif

#if HAS_BFDOT2
typedef __bf16 v2bf __attribute__((ext_vector_type(2)));
__device__ inline float bfdot2(uint a, uint b, float c) {
    union { uint u; v2bf v; } ua, ub;
    ua.u = a; ub.u = b;
    return __builtin_amdgcn_fdot2_f32_bf16(ua.v, ub.v, c, false);
}
#endif

__device__ inline ushort f2bf(float f) {
    union { __hip_bfloat16 b; ushort u; } cv;
    cv.b = __float2bfloat16(f);
    return cv.u;
}
__device__ inline float bflo(uint u) { union { uint i; float f; } c; c.i = u << 16; return c.f; }
__device__ inline float bfhi(uint u) { union { uint i; float f; } c; c.i = u & 0xffff0000u; return c.f; }

// ---------------------------------------------------------------------------
// K1: qkv = x @ w_qkv + b_qkv (q cols pre-scaled), bf16 out (R13 proven:
// BN=96, 40KB LDS, grid (128,4) -> 2 blocks/CU). Side job emits Wp_t.
// ---------------------------------------------------------------------------
__global__ __launch_bounds__(256) void qkv_gemm_fused_kernel(
    const float* __restrict__ x, const float* __restrict__ w_qkv,
    const float* __restrict__ b_qkv, const float* __restrict__ w_proj,
    ushort* __restrict__ qkv, ushort* __restrict__ Wp_t)
{
    __shared__ ushort S[64 * 128 + 96 * 128];   // As | Bs  (40KB)
    ushort* As = S;
    ushort* Bs = S + 64 * 128;

    const int tid = threadIdx.x;
    const int m0 = blockIdx.x * 64;
    const int n0 = blockIdx.y * 96;

    if (blockIdx.y == 0 && tid < 128)
        Wp_t[(size_t)blockIdx.x * 128 + tid] =
            f2bf(w_proj[(size_t)tid * 128 + blockIdx.x]);

    #pragma unroll
    for (int t = 0; t < 4; ++t) {
        int idx = tid + t * 256;
        int r = idx >> 4, c = idx & 15;
        const float* src = x + (size_t)(m0 + r) * 128 + c * 8;
        float4 v0 = *(const float4*)src;
        float4 v1 = *(const float4*)(src + 4);
        union { ushort s[8]; uint4 q; } u;
        u.s[0] = f2bf(v0.x); u.s[1] = f2bf(v0.y); u.s[2] = f2bf(v0.z); u.s[3] = f2bf(v0.w);
        u.s[4] = f2bf(v1.x); u.s[5] = f2bf(v1.y); u.s[6] = f2bf(v1.z); u.s[7] = f2bf(v1.w);
        *(uint4*)&As[r * 128 + (c ^ (r & 7)) * 8] = u.q;
    }
    #pragma unroll
    for (int t = 0; t < 6; ++t) {
        int idx = tid + t * 256;
        int kc = idx / 96, n = idx - kc * 96;
        union { ushort s[8]; uint4 q; } u;
        #pragma unroll
        for (int e = 0; e < 8; ++e)
            u.s[e] = f2bf(w_qkv[(size_t)(kc * 8 + e) * 384 + n0 + n]);
        *(uint4*)&Bs[n * 128 + ((kc ^ (n & 7)) * 8)] = u.q;
    }
    __syncthreads();

    const int wid = tid >> 6, lane = tid & 63;
    const int l15 = lane & 15, l4 = lane >> 4;
    const int mr = (wid >> 1) * 32, nr = (wid & 1) * 48;

    f32x4 acc[2][3] = {};
    #pragma unroll
    for (int ks = 0; ks < 4; ++ks) {
        short8 af[2], bf[3];
        #pragma unroll
        for (int fm = 0; fm < 2; ++fm) {
            int row = mr + fm * 16 + l15;
            af[fm] = *(const short8*)&As[row * 128 + ((ks * 4 + l4) ^ (row & 7)) * 8];
        }
        #pragma unroll
        for (int fn = 0; fn < 3; ++fn) {
            int row = nr + fn * 16 + l15;
            bf[fn] = *(const short8*)&Bs[row * 128 + ((ks * 4 + l4) ^ (row & 7)) * 8];
        }
        #pragma unroll
        for (int fm = 0; fm < 2; ++fm)
            #pragma unroll
            for (int fn = 0; fn < 3; ++fn)
                acc[fm][fn] = __builtin_amdgcn_mfma_f32_16x16x32_bf16(
                    af[fm], bf[fn], acc[fm][fn], 0, 0, 0);
    }

    __syncthreads();
    ushort* C_s = S;                      // 64 x 200 overlay
    #pragma unroll
    for (int fn = 0; fn < 3; ++fn) {
        int colb = nr + fn * 16;
        int col = colb + l15;
        float bc = b_qkv[n0 + col];
        float sc = (n0 + colb < 128) ? SCALE : 1.0f;
        #pragma unroll
        for (int fm = 0; fm < 2; ++fm)
            #pragma unroll
            for (int reg = 0; reg < 4; ++reg) {
                int row = mr + fm * 16 + l4 * 4 + reg;
                C_s[row * 200 + col] = f2bf((acc[fm][fn][reg] + bc) * sc);
            }
    }
    __syncthreads();
    #pragma unroll
    for (int t = 0; t < 3; ++t) {
        int idx = tid + t * 256;
        int row = idx / 12, c = idx - row * 12;
        uint4 v = *(const uint4*)&C_s[row * 200 + c * 8];
        *(uint4*)&qkv[(size_t)(m0 + row) * 384 + n0 + c * 8] = v;
    }
}

// ---------------------------------------------------------------------------
// K2: fused natten + proj, 512 threads = 8 waves, TWO waves per head.
// Waves 2h,2h+1 own head h; wave sub-half owns 16 queries; 4 lanes/query,
// j split by lane&3 (13 each). 2 waves/SIMD for latency hiding; VGPR capped
// at 128 via __launch_bounds__(512,2). KV slot formulas / AO swizzle / proj
// MFMA verbatim from the proven kernels. 2 barriers total.
// ---------------------------------------------------------------------------
__global__ __launch_bounds__(512, 2) void natten_proj_kernel(
    const ushort* __restrict__ qkv,     // (B*H*W) x 384 bf16, q pre-scaled
    const float* __restrict__ rpb,      // 4 x 13 x 13
    const ushort* __restrict__ Wp_t,    // 128 x 128 bf16, [n][k]
    const float* __restrict__ b_proj,   // 128
    float* __restrict__ out)            // (B*H*W) x 128 f32
{
    __shared__ ushort KV_s[4][NPIX * 64];  // 71.7KB (one quadrant per head)
    __shared__ ushort AO_s[NQ * 128];      // 8KB
    __shared__ float rpb_s[676];           // 2.7KB

    const int tid = threadIdx.x;
    const int wv = tid >> 6;               // wave 0..7
    const int hd = wv >> 1;                // head
    const int sub = wv & 1;                // query half
    const int lane = tid & 63;
    // XCD-aware swizzle (proven decode)
    const int bx = ((blockIdx.x & 7) << 5) | (blockIdx.x >> 3);
    const int b  = bx >> 7;
    const int th = (bx >> 3) & 15;
    const int tw = bx & 7;
    const int h0 = th * 4, w0 = tw * 8;
    const int ho = max(0, h0 - 3), wo = max(0, w0 - 3);

    #pragma unroll
    for (int t = 0; t < 2; ++t) {
        int idx = tid + t * 512;
        if (idx < 676) rpb_s[idx] = rpb[idx];
    }

    // ---- stage head hd's KV: 1120 granules over the head's 2 waves ----
    ushort* KV = &KV_s[hd][0];
    {
        const int sidx = sub * 64 + lane;      // 0..127 within head pair
        #pragma unroll
        for (int t = 0; t < 9; ++t) {
            int idx = sidx + t * 128;
            if (idx < NPIX * 8) {
                int pix = idx >> 3, s = idx & 7;
                int r = pix / HALO_W, c = pix - r * HALO_W;
                int gh = min(ho + r, HH - 1), gw = min(wo + c, WW - 1);
                const ushort* gp = qkv + (size_t)((b << 12) + (gh << 6) + gw) * 384
                                   + 128 + (s >> 2) * 128 + hd * 32 + (s & 3) * 8;
                uint4 v = *(const uint4*)gp;
                int bb = (pix >> 2) & 1;
                int slot = (2 * ((s & 3) ^ (pix & 3)) ^ bb) ^ (s >> 2);
                *(uint4*)&KV[pix * 64 + slot * 8] = v;
            }
        }
    }

    // per-lane query mapping: 4 lanes per query, j split by lane&3
    const int q = sub * 16 + (lane >> 2);
    const int t4 = lane & 3;
    const int qh = h0 + (q >> 3), qw = w0 + (q & 7);
    const int hs = min(max(qh - 3, 0), HH - 7);
    const int ws = min(max(qw - 3, 0), WW - 7);
    const int base_lp = (hs - ho) * HALO_W + (ws - wo);
    const int bh0 = hs - qh + 6, bw0 = ws - qw + 6;
    const size_t qpix = (size_t)((b << 12) + (qh << 6) + qw);

    // Q for head hd (issued during staging)
#if HAS_BFDOT2
    uint4 qb[4];
    #pragma unroll
    for (int d4 = 0; d4 < 4; ++d4)
        qb[d4] = *(const uint4*)(qkv + qpix * 384 + hd * 32 + d4 * 8);
#else
    float qf[32];
    #pragma unroll
    for (int d4 = 0; d4 < 4; ++d4) {
        uint4 qu = *(const uint4*)(qkv + qpix * 384 + hd * 32 + d4 * 8);
        qf[d4*8+0] = bflo(qu.x); qf[d4*8+1] = bfhi(qu.x);
        qf[d4*8+2] = bflo(qu.y); qf[d4*8+3] = bfhi(qu.y);
        qf[d4*8+4] = bflo(qu.z); qf[d4*8+5] = bfhi(qu.z);
        qf[d4*8+6] = bflo(qu.w); qf[d4*8+7] = bfhi(qu.w);
    }
#endif
    __syncthreads();   // barrier 1: all KV quadrants staged

    // ---- QK + bias: lane handles j = t4, t4+4, ... (13 js) ----
    float lg[13];
    #pragma unroll
    for (int i = 0; i < 13; ++i) {
        int j = t4 + 4 * i;
        float s = -1e30f;
        if (j < 49) {
            int p = (j * 37) >> 8;            // exact j/7 for j<=48
            int qq = j - p * 7;
            int lp = base_lp + p * HALO_W + qq;
            int bb = (lp >> 2) & 1;
            float a = 0.f;
            #pragma unroll
            for (int d4 = 0; d4 < 4; ++d4) {
                uint4 ku = *(const uint4*)&KV[lp * 64 + ((2 * (d4 ^ (lp & 3)) ^ bb) * 8)];
#if HAS_BFDOT2
                a = bfdot2(ku.x, qb[d4].x, a);
                a = bfdot2(ku.y, qb[d4].y, a);
                a = bfdot2(ku.z, qb[d4].z, a);
                a = bfdot2(ku.w, qb[d4].w, a);
#else
                a += bflo(ku.x)*qf[d4*8+0] + bfhi(ku.x)*qf[d4*8+1]
                   + bflo(ku.y)*qf[d4*8+2] + bfhi(ku.y)*qf[d4*8+3]
                   + bflo(ku.z)*qf[d4*8+4] + bfhi(ku.z)*qf[d4*8+5]
                   + bflo(ku.w)*qf[d4*8+6] + bfhi(ku.w)*qf[d4*8+7];
#endif
            }
            s = a + rpb_s[hd * 169 + (bh0 + p) * 13 + (bw0 + qq)];
        }
        lg[i] = s;
    }

    // ---- softmax across the query's 4 lanes (xor 1,2 stay in-group) ----
    float m = lg[0];
    #pragma unroll
    for (int i = 1; i < 13; ++i) m = fmaxf(m, lg[i]);
    m = fmaxf(m, __shfl_xor(m, 1));
    m = fmaxf(m, __shfl_xor(m, 2));
    float ssum = 0.f;
    #pragma unroll
    for (int i = 0; i < 13; ++i) {
        int j = t4 + 4 * i;
        lg[i] = (j < 49) ? __expf(lg[i] - m) : 0.f;
        ssum += lg[i];
    }
    ssum += __shfl_xor(ssum, 1);
    ssum += __shfl_xor(ssum, 2);
    float inv = 1.f / ssum;
    #pragma unroll
    for (int i = 0; i < 13; ++i) lg[i] *= inv;   // weights stay in regs

    // ---- PV: lane accumulates ALL 32 dims over its 13 js ----
    float o[32] = {};
    #pragma unroll
    for (int i = 0; i < 13; ++i) {
        int j = t4 + 4 * i;
        if (j < 49) {
            int p = (j * 37) >> 8;
            int qq = j - p * 7;
            int lp = base_lp + p * HALO_W + qq;
            int bb = (lp >> 2) & 1;
            float a = lg[i];
            #pragma unroll
            for (int d4 = 0; d4 < 4; ++d4) {
                uint4 vu = *(const uint4*)&KV[lp * 64 + (((2 * (d4 ^ (lp & 3)) ^ bb) ^ 1) * 8)];
                o[d4*8+0] += a * bflo(vu.x); o[d4*8+1] += a * bfhi(vu.x);
                o[d4*8+2] += a * bflo(vu.y); o[d4*8+3] += a * bfhi(vu.y);
                o[d4*8+4] += a * bflo(vu.z); o[d4*8+5] += a * bfhi(vu.z);
                o[d4*8+6] += a * bflo(vu.w); o[d4*8+7] += a * bfhi(vu.w);
            }
        }
    }
    // stage 1: pair-combine (xor 1), all 32 dims
    #pragma unroll
    for (int e = 0; e < 32; ++e) o[e] += __shfl_xor(o[e], 1);
    // stage 2: lane parity picks 16 dims, combine across xor(2)
    float t16v[16];
    const int dbase = (lane & 1) * 16;
    #pragma unroll
    for (int e = 0; e < 16; ++e) {
        float v = o[dbase + e];
        v += __shfl_xor(v, 2);
        t16v[e] = v;
    }

    if ((lane & 2) == 0) {
        #pragma unroll
        for (int cc = 0; cc < 2; ++cc) {
            int d4 = (lane & 1) * 2 + cc;
            union { ushort s[8]; uint4 u4; } w;
            #pragma unroll
            for (int e = 0; e < 8; ++e) w.s[e] = f2bf(t16v[cc * 8 + e]);
            // AO chunk index c = hd*4+d4 (0..15), proven (c ^ (q&7)) swizzle
            *(uint4*)&AO_s[q * 128 + (((hd * 4 + d4) ^ (q & 7)) * 8)] = w.u4;
        }
    }
    __syncthreads();   // barrier 2: AO complete

    // ---- proj: out(32x128) = AO @ Wp^T + b_proj, split across 8 waves ----
    const int l15 = lane & 15, l4 = lane >> 4;
    const int wr2 = wv >> 2;              // row half (16 rows)
    const int wc4 = wv & 3;               // col quarter (32 cols)

    f32x4 pacc[2] = {};
    #pragma unroll
    for (int ks = 0; ks < 4; ++ks) {
        int arow = wr2 * 16 + l15;
        short8 af = *(const short8*)&AO_s[arow * 128 + ((ks * 4 + l4) ^ (arow & 7)) * 8];
        #pragma unroll
        for (int fn = 0; fn < 2; ++fn) {
            int brow = wc4 * 32 + fn * 16 + l15;
            short8 bf = *(const short8*)(Wp_t + (size_t)brow * 128 + (ks * 4 + l4) * 8);
            pacc[fn] = __builtin_amdgcn_mfma_f32_16x16x32_bf16(af, bf, pacc[fn], 0, 0, 0);
        }
    }
    #pragma unroll
    for (int fn = 0; fn < 2; ++fn) {
        int col = wc4 * 32 + fn * 16 + l15;
        float bc = b_proj[col];
        #pragma unroll
        for (int reg = 0; reg < 4; ++reg) {
            int q2 = wr2 * 16 + l4 * 4 + reg;
            int oh = h0 + (q2 >> 3), ow = w0 + (q2 & 7);
            out[(size_t)((b << 12) + (oh << 6) + ow) * 128 + col] = pacc[fn][reg] + bc;
        }
    }
}

extern "C" void kernel_launch(void* const* d_in, const int* in_sizes, int n_in,
                              void* d_out, int out_size, void* d_ws, size_t ws_size,
                              hipStream_t stream)
{
    const float* x      = (const float*)d_in[0];
    const float* w_qkv  = (const float*)d_in[1];
    const float* b_qkv  = (const float*)d_in[2];
    const float* rpb    = (const float*)d_in[3];
    const float* w_proj = (const float*)d_in[4];
    const float* b_proj = (const float*)d_in[5];
    float* out = (float*)d_out;

    const int M = BB * HH * WW;                   // 8192
    ushort* qkv  = (ushort*)d_ws;                 // M x 384 bf16
    ushort* Wp_t = qkv + (size_t)M * 384;         // 128 x 128 bf16

    qkv_gemm_fused_kernel<<<dim3(128, 4), 256, 0, stream>>>(
        x, w_qkv, b_qkv, w_proj, qkv, Wp_t);

    natten_proj_kernel<<<256, 512, 0, stream>>>(
        qkv, rpb, Wp_t, b_proj, out);
}

// Round 17
// 48.808 us; speedup vs baseline: 11.6118x; 1.0056x over previous
//
#include <hip/hip_runtime.h>
#include <hip/hip_bf16.h>
#include <cstddef>

#define BB 2
#define HH 64
#define WW 64
#define SCALE 0.17677669529663687f   // 32^-0.5

// natten tile geometry: 4x8 queries per block
#define HALO_H 10
#define HALO_W 14
#define NPIX 140
#define NQ 32

typedef short short8 __attribute__((ext_vector_type(8)));
typedef float f32x4 __attribute__((ext_vector_type(4)));

#if defined(__has_builtin)
#if __has_builtin(__builtin_amdgcn_fdot2_f32_bf16)
#define HAS_BFDOT2 1
#endif
#endif
#ifndef HAS_BFDOT2
#define HAS_BFDOT2 0
#endif

#if HAS_BFDOT2
typedef __bf16 v2bf __attribute__((ext_vector_type(2)));
__device__ inline float bfdot2(uint a, uint b, float c) {
    union { uint u; v2bf v; } ua, ub;
    ua.u = a; ub.u = b;
    return __builtin_amdgcn_fdot2_f32_bf16(ua.v, ub.v, c, false);
}
#endif

__device__ inline ushort f2bf(float f) {
    union { __hip_bfloat16 b; ushort u; } cv;
    cv.b = __float2bfloat16(f);
    return cv.u;
}
__device__ inline float bflo(uint u) { union { uint i; float f; } c; c.i = u << 16; return c.f; }
__device__ inline float bfhi(uint u) { union { uint i; float f; } c; c.i = u & 0xffff0000u; return c.f; }

// ---------------------------------------------------------------------------
// K1: qkv = x @ w_qkv + b_qkv (q cols pre-scaled), bf16 out (R13 proven:
// BN=96, 40KB LDS, grid (128,4) -> 2 blocks/CU). Side job emits Wp_t.
// ---------------------------------------------------------------------------
__global__ __launch_bounds__(256) void qkv_gemm_fused_kernel(
    const float* __restrict__ x, const float* __restrict__ w_qkv,
    const float* __restrict__ b_qkv, const float* __restrict__ w_proj,
    ushort* __restrict__ qkv, ushort* __restrict__ Wp_t)
{
    __shared__ ushort S[64 * 128 + 96 * 128];   // As | Bs  (40KB)
    ushort* As = S;
    ushort* Bs = S + 64 * 128;

    const int tid = threadIdx.x;
    const int m0 = blockIdx.x * 64;
    const int n0 = blockIdx.y * 96;

    if (blockIdx.y == 0 && tid < 128)
        Wp_t[(size_t)blockIdx.x * 128 + tid] =
            f2bf(w_proj[(size_t)tid * 128 + blockIdx.x]);

    #pragma unroll
    for (int t = 0; t < 4; ++t) {
        int idx = tid + t * 256;
        int r = idx >> 4, c = idx & 15;
        const float* src = x + (size_t)(m0 + r) * 128 + c * 8;
        float4 v0 = *(const float4*)src;
        float4 v1 = *(const float4*)(src + 4);
        union { ushort s[8]; uint4 q; } u;
        u.s[0] = f2bf(v0.x); u.s[1] = f2bf(v0.y); u.s[2] = f2bf(v0.z); u.s[3] = f2bf(v0.w);
        u.s[4] = f2bf(v1.x); u.s[5] = f2bf(v1.y); u.s[6] = f2bf(v1.z); u.s[7] = f2bf(v1.w);
        *(uint4*)&As[r * 128 + (c ^ (r & 7)) * 8] = u.q;
    }
    #pragma unroll
    for (int t = 0; t < 6; ++t) {
        int idx = tid + t * 256;
        int kc = idx / 96, n = idx - kc * 96;
        union { ushort s[8]; uint4 q; } u;
        #pragma unroll
        for (int e = 0; e < 8; ++e)
            u.s[e] = f2bf(w_qkv[(size_t)(kc * 8 + e) * 384 + n0 + n]);
        *(uint4*)&Bs[n * 128 + ((kc ^ (n & 7)) * 8)] = u.q;
    }
    __syncthreads();

    const int wid = tid >> 6, lane = tid & 63;
    const int l15 = lane & 15, l4 = lane >> 4;
    const int mr = (wid >> 1) * 32, nr = (wid & 1) * 48;

    f32x4 acc[2][3] = {};
    #pragma unroll
    for (int ks = 0; ks < 4; ++ks) {
        short8 af[2], bf[3];
        #pragma unroll
        for (int fm = 0; fm < 2; ++fm) {
            int row = mr + fm * 16 + l15;
            af[fm] = *(const short8*)&As[row * 128 + ((ks * 4 + l4) ^ (row & 7)) * 8];
        }
        #pragma unroll
        for (int fn = 0; fn < 3; ++fn) {
            int row = nr + fn * 16 + l15;
            bf[fn] = *(const short8*)&Bs[row * 128 + ((ks * 4 + l4) ^ (row & 7)) * 8];
        }
        #pragma unroll
        for (int fm = 0; fm < 2; ++fm)
            #pragma unroll
            for (int fn = 0; fn < 3; ++fn)
                acc[fm][fn] = __builtin_amdgcn_mfma_f32_16x16x32_bf16(
                    af[fm], bf[fn], acc[fm][fn], 0, 0, 0);
    }

    __syncthreads();
    ushort* C_s = S;                      // 64 x 200 overlay
    #pragma unroll
    for (int fn = 0; fn < 3; ++fn) {
        int colb = nr + fn * 16;
        int col = colb + l15;
        float bc = b_qkv[n0 + col];
        float sc = (n0 + colb < 128) ? SCALE : 1.0f;
        #pragma unroll
        for (int fm = 0; fm < 2; ++fm)
            #pragma unroll
            for (int reg = 0; reg < 4; ++reg) {
                int row = mr + fm * 16 + l4 * 4 + reg;
                C_s[row * 200 + col] = f2bf((acc[fm][fn][reg] + bc) * sc);
            }
    }
    __syncthreads();
    #pragma unroll
    for (int t = 0; t < 3; ++t) {
        int idx = tid + t * 256;
        int row = idx / 12, c = idx - row * 12;
        uint4 v = *(const uint4*)&C_s[row * 200 + c * 8];
        *(uint4*)&qkv[(size_t)(m0 + row) * 384 + n0 + c * 8] = v;
    }
}

// ---------------------------------------------------------------------------
// K2: fused natten + proj, 512 threads = 8 waves, TWO waves per head
// (R16 structure). SINGLE CHANGE vs R16: __launch_bounds__(512, 1) --
// the (512,2) bound capped VGPR at 128 and spilled ~65MB to scratch
// (R16 counters: WRITE 69.6MB, FETCH 36.7MB). With 256-VGPR headroom the
// ~77-reg live state fits; HW still co-resides 2 waves/SIMD (<=256 VGPR).
// ---------------------------------------------------------------------------
__global__ __launch_bounds__(512, 1) void natten_proj_kernel(
    const ushort* __restrict__ qkv,     // (B*H*W) x 384 bf16, q pre-scaled
    const float* __restrict__ rpb,      // 4 x 13 x 13
    const ushort* __restrict__ Wp_t,    // 128 x 128 bf16, [n][k]
    const float* __restrict__ b_proj,   // 128
    float* __restrict__ out)            // (B*H*W) x 128 f32
{
    __shared__ ushort KV_s[4][NPIX * 64];  // 71.7KB (one quadrant per head)
    __shared__ ushort AO_s[NQ * 128];      // 8KB
    __shared__ float rpb_s[676];           // 2.7KB

    const int tid = threadIdx.x;
    const int wv = tid >> 6;               // wave 0..7
    const int hd = wv >> 1;                // head
    const int sub = wv & 1;                // query half
    const int lane = tid & 63;
    // XCD-aware swizzle (proven decode)
    const int bx = ((blockIdx.x & 7) << 5) | (blockIdx.x >> 3);
    const int b  = bx >> 7;
    const int th = (bx >> 3) & 15;
    const int tw = bx & 7;
    const int h0 = th * 4, w0 = tw * 8;
    const int ho = max(0, h0 - 3), wo = max(0, w0 - 3);

    #pragma unroll
    for (int t = 0; t < 2; ++t) {
        int idx = tid + t * 512;
        if (idx < 676) rpb_s[idx] = rpb[idx];
    }

    // ---- stage head hd's KV: 1120 granules over the head's 2 waves ----
    ushort* KV = &KV_s[hd][0];
    {
        const int sidx = sub * 64 + lane;      // 0..127 within head pair
        #pragma unroll
        for (int t = 0; t < 9; ++t) {
            int idx = sidx + t * 128;
            if (idx < NPIX * 8) {
                int pix = idx >> 3, s = idx & 7;
                int r = pix / HALO_W, c = pix - r * HALO_W;
                int gh = min(ho + r, HH - 1), gw = min(wo + c, WW - 1);
                const ushort* gp = qkv + (size_t)((b << 12) + (gh << 6) + gw) * 384
                                   + 128 + (s >> 2) * 128 + hd * 32 + (s & 3) * 8;
                uint4 v = *(const uint4*)gp;
                int bb = (pix >> 2) & 1;
                int slot = (2 * ((s & 3) ^ (pix & 3)) ^ bb) ^ (s >> 2);
                *(uint4*)&KV[pix * 64 + slot * 8] = v;
            }
        }
    }

    // per-lane query mapping: 4 lanes per query, j split by lane&3
    const int q = sub * 16 + (lane >> 2);
    const int t4 = lane & 3;
    const int qh = h0 + (q >> 3), qw = w0 + (q & 7);
    const int hs = min(max(qh - 3, 0), HH - 7);
    const int ws = min(max(qw - 3, 0), WW - 7);
    const int base_lp = (hs - ho) * HALO_W + (ws - wo);
    const int bh0 = hs - qh + 6, bw0 = ws - qw + 6;
    const size_t qpix = (size_t)((b << 12) + (qh << 6) + qw);

    // Q for head hd (issued during staging)
#if HAS_BFDOT2
    uint4 qb[4];
    #pragma unroll
    for (int d4 = 0; d4 < 4; ++d4)
        qb[d4] = *(const uint4*)(qkv + qpix * 384 + hd * 32 + d4 * 8);
#else
    float qf[32];
    #pragma unroll
    for (int d4 = 0; d4 < 4; ++d4) {
        uint4 qu = *(const uint4*)(qkv + qpix * 384 + hd * 32 + d4 * 8);
        qf[d4*8+0] = bflo(qu.x); qf[d4*8+1] = bfhi(qu.x);
        qf[d4*8+2] = bflo(qu.y); qf[d4*8+3] = bfhi(qu.y);
        qf[d4*8+4] = bflo(qu.z); qf[d4*8+5] = bfhi(qu.z);
        qf[d4*8+6] = bflo(qu.w); qf[d4*8+7] = bfhi(qu.w);
    }
#endif
    __syncthreads();   // barrier 1: all KV quadrants staged

    // ---- QK + bias: lane handles j = t4, t4+4, ... (13 js) ----
    float lg[13];
    #pragma unroll
    for (int i = 0; i < 13; ++i) {
        int j = t4 + 4 * i;
        float s = -1e30f;
        if (j < 49) {
            int p = (j * 37) >> 8;            // exact j/7 for j<=48
            int qq = j - p * 7;
            int lp = base_lp + p * HALO_W + qq;
            int bb = (lp >> 2) & 1;
            float a = 0.f;
            #pragma unroll
            for (int d4 = 0; d4 < 4; ++d4) {
                uint4 ku = *(const uint4*)&KV[lp * 64 + ((2 * (d4 ^ (lp & 3)) ^ bb) * 8)];
#if HAS_BFDOT2
                a = bfdot2(ku.x, qb[d4].x, a);
                a = bfdot2(ku.y, qb[d4].y, a);
                a = bfdot2(ku.z, qb[d4].z, a);
                a = bfdot2(ku.w, qb[d4].w, a);
#else
                a += bflo(ku.x)*qf[d4*8+0] + bfhi(ku.x)*qf[d4*8+1]
                   + bflo(ku.y)*qf[d4*8+2] + bfhi(ku.y)*qf[d4*8+3]
                   + bflo(ku.z)*qf[d4*8+4] + bfhi(ku.z)*qf[d4*8+5]
                   + bflo(ku.w)*qf[d4*8+6] + bfhi(ku.w)*qf[d4*8+7];
#endif
            }
            s = a + rpb_s[hd * 169 + (bh0 + p) * 13 + (bw0 + qq)];
        }
        lg[i] = s;
    }

    // ---- softmax across the query's 4 lanes (xor 1,2 stay in-group) ----
    float m = lg[0];
    #pragma unroll
    for (int i = 1; i < 13; ++i) m = fmaxf(m, lg[i]);
    m = fmaxf(m, __shfl_xor(m, 1));
    m = fmaxf(m, __shfl_xor(m, 2));
    float ssum = 0.f;
    #pragma unroll
    for (int i = 0; i < 13; ++i) {
        int j = t4 + 4 * i;
        lg[i] = (j < 49) ? __expf(lg[i] - m) : 0.f;
        ssum += lg[i];
    }
    ssum += __shfl_xor(ssum, 1);
    ssum += __shfl_xor(ssum, 2);
    float inv = 1.f / ssum;
    #pragma unroll
    for (int i = 0; i < 13; ++i) lg[i] *= inv;   // weights stay in regs

    // ---- PV: lane accumulates ALL 32 dims over its 13 js ----
    float o[32] = {};
    #pragma unroll
    for (int i = 0; i < 13; ++i) {
        int j = t4 + 4 * i;
        if (j < 49) {
            int p = (j * 37) >> 8;
            int qq = j - p * 7;
            int lp = base_lp + p * HALO_W + qq;
            int bb = (lp >> 2) & 1;
            float a = lg[i];
            #pragma unroll
            for (int d4 = 0; d4 < 4; ++d4) {
                uint4 vu = *(const uint4*)&KV[lp * 64 + (((2 * (d4 ^ (lp & 3)) ^ bb) ^ 1) * 8)];
                o[d4*8+0] += a * bflo(vu.x); o[d4*8+1] += a * bfhi(vu.x);
                o[d4*8+2] += a * bflo(vu.y); o[d4*8+3] += a * bfhi(vu.y);
                o[d4*8+4] += a * bflo(vu.z); o[d4*8+5] += a * bfhi(vu.z);
                o[d4*8+6] += a * bflo(vu.w); o[d4*8+7] += a * bfhi(vu.w);
            }
        }
    }
    // stage 1: pair-combine (xor 1), all 32 dims
    #pragma unroll
    for (int e = 0; e < 32; ++e) o[e] += __shfl_xor(o[e], 1);
    // stage 2: lane parity picks 16 dims, combine across xor(2)
    float t16v[16];
    const int dbase = (lane & 1) * 16;
    #pragma unroll
    for (int e = 0; e < 16; ++e) {
        float v = o[dbase + e];
        v += __shfl_xor(v, 2);
        t16v[e] = v;
    }

    if ((lane & 2) == 0) {
        #pragma unroll
        for (int cc = 0; cc < 2; ++cc) {
            int d4 = (lane & 1) * 2 + cc;
            union { ushort s[8]; uint4 u4; } w;
            #pragma unroll
            for (int e = 0; e < 8; ++e) w.s[e] = f2bf(t16v[cc * 8 + e]);
            // AO chunk index c = hd*4+d4 (0..15), proven (c ^ (q&7)) swizzle
            *(uint4*)&AO_s[q * 128 + (((hd * 4 + d4) ^ (q & 7)) * 8)] = w.u4;
        }
    }
    __syncthreads();   // barrier 2: AO complete

    // ---- proj: out(32x128) = AO @ Wp^T + b_proj, split across 8 waves ----
    const int l15 = lane & 15, l4 = lane >> 4;
    const int wr2 = wv >> 2;              // row half (16 rows)
    const int wc4 = wv & 3;               // col quarter (32 cols)

    f32x4 pacc[2] = {};
    #pragma unroll
    for (int ks = 0; ks < 4; ++ks) {
        int arow = wr2 * 16 + l15;
        short8 af = *(const short8*)&AO_s[arow * 128 + ((ks * 4 + l4) ^ (arow & 7)) * 8];
        #pragma unroll
        for (int fn = 0; fn < 2; ++fn) {
            int brow = wc4 * 32 + fn * 16 + l15;
            short8 bf = *(const short8*)(Wp_t + (size_t)brow * 128 + (ks * 4 + l4) * 8);
            pacc[fn] = __builtin_amdgcn_mfma_f32_16x16x32_bf16(af, bf, pacc[fn], 0, 0, 0);
        }
    }
    #pragma unroll
    for (int fn = 0; fn < 2; ++fn) {
        int col = wc4 * 32 + fn * 16 + l15;
        float bc = b_proj[col];
        #pragma unroll
        for (int reg = 0; reg < 4; ++reg) {
            int q2 = wr2 * 16 + l4 * 4 + reg;
            int oh = h0 + (q2 >> 3), ow = w0 + (q2 & 7);
            out[(size_t)((b << 12) + (oh << 6) + ow) * 128 + col] = pacc[fn][reg] + bc;
        }
    }
}

extern "C" void kernel_launch(void* const* d_in, const int* in_sizes, int n_in,
                              void* d_out, int out_size, void* d_ws, size_t ws_size,
                              hipStream_t stream)
{
    const float* x      = (const float*)d_in[0];
    const float* w_qkv  = (const float*)d_in[1];
    const float* b_qkv  = (const float*)d_in[2];
    const float* rpb    = (const float*)d_in[3];
    const float* w_proj = (const float*)d_in[4];
    const float* b_proj = (const float*)d_in[5];
    float* out = (float*)d_out;

    const int M = BB * HH * WW;                   // 8192
    ushort* qkv  = (ushort*)d_ws;                 // M x 384 bf16
    ushort* Wp_t = qkv + (size_t)M * 384;         // 128 x 128 bf16

    qkv_gemm_fused_kernel<<<dim3(128, 4), 256, 0, stream>>>(
        x, w_qkv, b_qkv, w_proj, qkv, Wp_t);

    natten_proj_kernel<<<256, 512, 0, stream>>>(
        qkv, rpb, Wp_t, b_proj, out);
}

// Round 18
// 24.287 us; speedup vs baseline: 23.3350x; 2.0096x over previous
//
#include <hip/hip_runtime.h>
#include <hip/hip_bf16.h>
#include <cstddef>

#define BB 2
#define HH 64
#define WW 64
#define SCALE 0.17677669529663687f   // 32^-0.5

// natten tile geometry: 4x8 queries per block
#define HALO_H 10
#define HALO_W 14
#define NPIX 140
#define NQ 32

typedef short short8 __attribute__((ext_vector_type(8)));
typedef float f32x4 __attribute__((ext_vector_type(4)));

#if defined(__has_builtin)
#if __has_builtin(__builtin_amdgcn_fdot2_f32_bf16)
#define HAS_BFDOT2 1
#endif
#endif
#ifndef HAS_BFDOT2
#define HAS_BFDOT2 0
#endif

#if HAS_BFDOT2
typedef __bf16 v2bf __attribute__((ext_vector_type(2)));
__device__ inline float bfdot2(uint a, uint b, float c) {
    union { uint u; v2bf v; } ua, ub;
    ua.u = a; ub.u = b;
    return __builtin_amdgcn_fdot2_f32_bf16(ua.v, ub.v, c, false);
}
#endif

__device__ inline ushort f2bf(float f) {
    union { __hip_bfloat16 b; ushort u; } cv;
    cv.b = __float2bfloat16(f);
    return cv.u;
}
__device__ inline float bflo(uint u) { union { uint i; float f; } c; c.i = u << 16; return c.f; }
__device__ inline float bfhi(uint u) { union { uint i; float f; } c; c.i = u & 0xffff0000u; return c.f; }

// ---------------------------------------------------------------------------
// K1: qkv = x @ w_qkv + b_qkv (q cols pre-scaled), bf16 out (R13 proven:
// BN=96, 40KB LDS, grid (128,4) -> 2 blocks/CU). Side job emits Wp_t.
// ---------------------------------------------------------------------------
__global__ __launch_bounds__(256) void qkv_gemm_fused_kernel(
    const float* __restrict__ x, const float* __restrict__ w_qkv,
    const float* __restrict__ b_qkv, const float* __restrict__ w_proj,
    ushort* __restrict__ qkv, ushort* __restrict__ Wp_t)
{
    __shared__ ushort S[64 * 128 + 96 * 128];   // As | Bs  (40KB)
    ushort* As = S;
    ushort* Bs = S + 64 * 128;

    const int tid = threadIdx.x;
    const int m0 = blockIdx.x * 64;
    const int n0 = blockIdx.y * 96;

    if (blockIdx.y == 0 && tid < 128)
        Wp_t[(size_t)blockIdx.x * 128 + tid] =
            f2bf(w_proj[(size_t)tid * 128 + blockIdx.x]);

    #pragma unroll
    for (int t = 0; t < 4; ++t) {
        int idx = tid + t * 256;
        int r = idx >> 4, c = idx & 15;
        const float* src = x + (size_t)(m0 + r) * 128 + c * 8;
        float4 v0 = *(const float4*)src;
        float4 v1 = *(const float4*)(src + 4);
        union { ushort s[8]; uint4 q; } u;
        u.s[0] = f2bf(v0.x); u.s[1] = f2bf(v0.y); u.s[2] = f2bf(v0.z); u.s[3] = f2bf(v0.w);
        u.s[4] = f2bf(v1.x); u.s[5] = f2bf(v1.y); u.s[6] = f2bf(v1.z); u.s[7] = f2bf(v1.w);
        *(uint4*)&As[r * 128 + (c ^ (r & 7)) * 8] = u.q;
    }
    #pragma unroll
    for (int t = 0; t < 6; ++t) {
        int idx = tid + t * 256;
        int kc = idx / 96, n = idx - kc * 96;
        union { ushort s[8]; uint4 q; } u;
        #pragma unroll
        for (int e = 0; e < 8; ++e)
            u.s[e] = f2bf(w_qkv[(size_t)(kc * 8 + e) * 384 + n0 + n]);
        *(uint4*)&Bs[n * 128 + ((kc ^ (n & 7)) * 8)] = u.q;
    }
    __syncthreads();

    const int wid = tid >> 6, lane = tid & 63;
    const int l15 = lane & 15, l4 = lane >> 4;
    const int mr = (wid >> 1) * 32, nr = (wid & 1) * 48;

    f32x4 acc[2][3] = {};
    #pragma unroll
    for (int ks = 0; ks < 4; ++ks) {
        short8 af[2], bf[3];
        #pragma unroll
        for (int fm = 0; fm < 2; ++fm) {
            int row = mr + fm * 16 + l15;
            af[fm] = *(const short8*)&As[row * 128 + ((ks * 4 + l4) ^ (row & 7)) * 8];
        }
        #pragma unroll
        for (int fn = 0; fn < 3; ++fn) {
            int row = nr + fn * 16 + l15;
            bf[fn] = *(const short8*)&Bs[row * 128 + ((ks * 4 + l4) ^ (row & 7)) * 8];
        }
        #pragma unroll
        for (int fm = 0; fm < 2; ++fm)
            #pragma unroll
            for (int fn = 0; fn < 3; ++fn)
                acc[fm][fn] = __builtin_amdgcn_mfma_f32_16x16x32_bf16(
                    af[fm], bf[fn], acc[fm][fn], 0, 0, 0);
    }

    __syncthreads();
    ushort* C_s = S;                      // 64 x 200 overlay
    #pragma unroll
    for (int fn = 0; fn < 3; ++fn) {
        int colb = nr + fn * 16;
        int col = colb + l15;
        float bc = b_qkv[n0 + col];
        float sc = (n0 + colb < 128) ? SCALE : 1.0f;
        #pragma unroll
        for (int fm = 0; fm < 2; ++fm)
            #pragma unroll
            for (int reg = 0; reg < 4; ++reg) {
                int row = mr + fm * 16 + l4 * 4 + reg;
                C_s[row * 200 + col] = f2bf((acc[fm][fn][reg] + bc) * sc);
            }
    }
    __syncthreads();
    #pragma unroll
    for (int t = 0; t < 3; ++t) {
        int idx = tid + t * 256;
        int row = idx / 12, c = idx - row * 12;
        uint4 v = *(const uint4*)&C_s[row * 200 + c * 8];
        *(uint4*)&qkv[(size_t)(m0 + row) * 384 + n0 + c * 8] = v;
    }
}

// ---------------------------------------------------------------------------
// K2: fused natten + proj, 512 threads = 8 waves, two waves per head
// (R16/R17 structure). CHANGE vs R17: PV quad-role split -- jp=t4>>1 owns a
// j-parity (25 js), dh=t4&1 owns a 16-dim half -> o[16] not o[32], t16v
// eliminated; weights redistributed from the QK split via __shfl. Live
// state ~90 regs < the 128-VGPR cap hipcc imposes on 512-thread blocks
// (R16/R17 spilled ~65MB scratch at o[32]).
// ---------------------------------------------------------------------------
__global__ __launch_bounds__(512, 2) void natten_proj_kernel(
    const ushort* __restrict__ qkv,     // (B*H*W) x 384 bf16, q pre-scaled
    const float* __restrict__ rpb,      // 4 x 13 x 13
    const ushort* __restrict__ Wp_t,    // 128 x 128 bf16, [n][k]
    const float* __restrict__ b_proj,   // 128
    float* __restrict__ out)            // (B*H*W) x 128 f32
{
    __shared__ ushort KV_s[4][NPIX * 64];  // 71.7KB (one quadrant per head)
    __shared__ ushort AO_s[NQ * 128];      // 8KB
    __shared__ float rpb_s[676];           // 2.7KB

    const int tid = threadIdx.x;
    const int wv = tid >> 6;               // wave 0..7
    const int hd = wv >> 1;                // head
    const int sub = wv & 1;                // query half
    const int lane = tid & 63;
    // XCD-aware swizzle (proven decode)
    const int bx = ((blockIdx.x & 7) << 5) | (blockIdx.x >> 3);
    const int b  = bx >> 7;
    const int th = (bx >> 3) & 15;
    const int tw = bx & 7;
    const int h0 = th * 4, w0 = tw * 8;
    const int ho = max(0, h0 - 3), wo = max(0, w0 - 3);

    #pragma unroll
    for (int t = 0; t < 2; ++t) {
        int idx = tid + t * 512;
        if (idx < 676) rpb_s[idx] = rpb[idx];
    }

    // ---- stage head hd's KV: 1120 granules over the head's 2 waves ----
    ushort* KV = &KV_s[hd][0];
    {
        const int sidx = sub * 64 + lane;      // 0..127 within head pair
        #pragma unroll
        for (int t = 0; t < 9; ++t) {
            int idx = sidx + t * 128;
            if (idx < NPIX * 8) {
                int pix = idx >> 3, s = idx & 7;
                int r = pix / HALO_W, c = pix - r * HALO_W;
                int gh = min(ho + r, HH - 1), gw = min(wo + c, WW - 1);
                const ushort* gp = qkv + (size_t)((b << 12) + (gh << 6) + gw) * 384
                                   + 128 + (s >> 2) * 128 + hd * 32 + (s & 3) * 8;
                uint4 v = *(const uint4*)gp;
                int bb = (pix >> 2) & 1;
                int slot = (2 * ((s & 3) ^ (pix & 3)) ^ bb) ^ (s >> 2);
                *(uint4*)&KV[pix * 64 + slot * 8] = v;
            }
        }
    }

    // per-lane query mapping: 4 lanes per query, QK j split by lane&3
    const int q = sub * 16 + (lane >> 2);
    const int t4 = lane & 3;
    const int qh = h0 + (q >> 3), qw = w0 + (q & 7);
    const int hs = min(max(qh - 3, 0), HH - 7);
    const int ws = min(max(qw - 3, 0), WW - 7);
    const int base_lp = (hs - ho) * HALO_W + (ws - wo);
    const int bh0 = hs - qh + 6, bw0 = ws - qw + 6;
    const size_t qpix = (size_t)((b << 12) + (qh << 6) + qw);

    // Q for head hd (issued during staging)
#if HAS_BFDOT2
    uint4 qb[4];
    #pragma unroll
    for (int d4 = 0; d4 < 4; ++d4)
        qb[d4] = *(const uint4*)(qkv + qpix * 384 + hd * 32 + d4 * 8);
#else
    float qf[32];
    #pragma unroll
    for (int d4 = 0; d4 < 4; ++d4) {
        uint4 qu = *(const uint4*)(qkv + qpix * 384 + hd * 32 + d4 * 8);
        qf[d4*8+0] = bflo(qu.x); qf[d4*8+1] = bfhi(qu.x);
        qf[d4*8+2] = bflo(qu.y); qf[d4*8+3] = bfhi(qu.y);
        qf[d4*8+4] = bflo(qu.z); qf[d4*8+5] = bfhi(qu.z);
        qf[d4*8+6] = bflo(qu.w); qf[d4*8+7] = bfhi(qu.w);
    }
#endif
    __syncthreads();   // barrier 1: all KV quadrants staged

    // ---- QK + bias: lane handles j = t4, t4+4, ... (13 js) ----
    float lg[13];
    #pragma unroll
    for (int i = 0; i < 13; ++i) {
        int j = t4 + 4 * i;
        float s = -1e30f;
        if (j < 49) {
            int p = (j * 37) >> 8;            // exact j/7 for j<=48
            int qq = j - p * 7;
            int lp = base_lp + p * HALO_W + qq;
            int bb = (lp >> 2) & 1;
            float a = 0.f;
            #pragma unroll
            for (int d4 = 0; d4 < 4; ++d4) {
                uint4 ku = *(const uint4*)&KV[lp * 64 + ((2 * (d4 ^ (lp & 3)) ^ bb) * 8)];
#if HAS_BFDOT2
                a = bfdot2(ku.x, qb[d4].x, a);
                a = bfdot2(ku.y, qb[d4].y, a);
                a = bfdot2(ku.z, qb[d4].z, a);
                a = bfdot2(ku.w, qb[d4].w, a);
#else
                a += bflo(ku.x)*qf[d4*8+0] + bfhi(ku.x)*qf[d4*8+1]
                   + bflo(ku.y)*qf[d4*8+2] + bfhi(ku.y)*qf[d4*8+3]
                   + bflo(ku.z)*qf[d4*8+4] + bfhi(ku.z)*qf[d4*8+5]
                   + bflo(ku.w)*qf[d4*8+6] + bfhi(ku.w)*qf[d4*8+7];
#endif
            }
            s = a + rpb_s[hd * 169 + (bh0 + p) * 13 + (bw0 + qq)];
        }
        lg[i] = s;
    }

    // ---- softmax across the query's 4 lanes (xor 1,2 stay in-group) ----
    float m = lg[0];
    #pragma unroll
    for (int i = 1; i < 13; ++i) m = fmaxf(m, lg[i]);
    m = fmaxf(m, __shfl_xor(m, 1));
    m = fmaxf(m, __shfl_xor(m, 2));
    float ssum = 0.f;
    #pragma unroll
    for (int i = 0; i < 13; ++i) {
        int j = t4 + 4 * i;
        lg[i] = (j < 49) ? __expf(lg[i] - m) : 0.f;
        ssum += lg[i];
    }
    ssum += __shfl_xor(ssum, 1);
    ssum += __shfl_xor(ssum, 2);
    float inv = 1.f / ssum;
    #pragma unroll
    for (int i = 0; i < 13; ++i) lg[i] *= inv;   // weights stay in regs

    // ---- PV: quad roles jp=t4>>1 (j-parity, 25 js), dh=t4&1 (16 dims) ----
    const int jp = t4 >> 1;
    const int dh = t4 & 1;
    float o[16] = {};
    #pragma unroll
    for (int i = 0; i < 25; ++i) {
        int j = jp + 2 * i;
        if (j < 49) {
            // weight for j lives in quad-lane (jp + 2*(i&1)) at index i>>1:
            // j mod 4 = jp + 2*(i&1);  j = (j mod 4) + 4*(i>>1)
            int srcl = (lane & ~3) | (jp + 2 * (i & 1));
            float a = __shfl(lg[i >> 1], srcl);
            int p = (j * 37) >> 8;
            int qq = j - p * 7;
            int lp = base_lp + p * HALO_W + qq;
            int bb = (lp >> 2) & 1;
            #pragma unroll
            for (int c2 = 0; c2 < 2; ++c2) {
                int d4 = dh * 2 + c2;
                uint4 vu = *(const uint4*)&KV[lp * 64 + (((2 * (d4 ^ (lp & 3)) ^ bb) ^ 1) * 8)];
                o[c2*8+0] += a * bflo(vu.x); o[c2*8+1] += a * bfhi(vu.x);
                o[c2*8+2] += a * bflo(vu.y); o[c2*8+3] += a * bfhi(vu.y);
                o[c2*8+4] += a * bflo(vu.z); o[c2*8+5] += a * bfhi(vu.z);
                o[c2*8+6] += a * bflo(vu.w); o[c2*8+7] += a * bfhi(vu.w);
            }
        }
    }
    // combine j-parities: lanes t4 and t4^2 share dh
    #pragma unroll
    for (int e = 0; e < 16; ++e) o[e] += __shfl_xor(o[e], 2);

    if (t4 < 2) {                          // jp==0 lanes write; dh == t4
        #pragma unroll
        for (int cc = 0; cc < 2; ++cc) {
            int d4 = dh * 2 + cc;
            union { ushort s[8]; uint4 u4; } w;
            #pragma unroll
            for (int e = 0; e < 8; ++e) w.s[e] = f2bf(o[cc * 8 + e]);
            // AO chunk index c = hd*4+d4 (0..15), proven (c ^ (q&7)) swizzle
            *(uint4*)&AO_s[q * 128 + (((hd * 4 + d4) ^ (q & 7)) * 8)] = w.u4;
        }
    }
    __syncthreads();   // barrier 2: AO complete

    // ---- proj: out(32x128) = AO @ Wp^T + b_proj, split across 8 waves ----
    const int l15 = lane & 15, l4 = lane >> 4;
    const int wr2 = wv >> 2;              // row half (16 rows)
    const int wc4 = wv & 3;               // col quarter (32 cols)

    f32x4 pacc[2] = {};
    #pragma unroll
    for (int ks = 0; ks < 4; ++ks) {
        int arow = wr2 * 16 + l15;
        short8 af = *(const short8*)&AO_s[arow * 128 + ((ks * 4 + l4) ^ (arow & 7)) * 8];
        #pragma unroll
        for (int fn = 0; fn < 2; ++fn) {
            int brow = wc4 * 32 + fn * 16 + l15;
            short8 bf = *(const short8*)(Wp_t + (size_t)brow * 128 + (ks * 4 + l4) * 8);
            pacc[fn] = __builtin_amdgcn_mfma_f32_16x16x32_bf16(af, bf, pacc[fn], 0, 0, 0);
        }
    }
    #pragma unroll
    for (int fn = 0; fn < 2; ++fn) {
        int col = wc4 * 32 + fn * 16 + l15;
        float bc = b_proj[col];
        #pragma unroll
        for (int reg = 0; reg < 4; ++reg) {
            int q2 = wr2 * 16 + l4 * 4 + reg;
            int oh = h0 + (q2 >> 3), ow = w0 + (q2 & 7);
            out[(size_t)((b << 12) + (oh << 6) + ow) * 128 + col] = pacc[fn][reg] + bc;
        }
    }
}

extern "C" void kernel_launch(void* const* d_in, const int* in_sizes, int n_in,
                              void* d_out, int out_size, void* d_ws, size_t ws_size,
                              hipStream_t stream)
{
    const float* x      = (const float*)d_in[0];
    const float* w_qkv  = (const float*)d_in[1];
    const float* b_qkv  = (const float*)d_in[2];
    const float* rpb    = (const float*)d_in[3];
    const float* w_proj = (const float*)d_in[4];
    const float* b_proj = (const float*)d_in[5];
    float* out = (float*)d_out;

    const int M = BB * HH * WW;                   // 8192
    ushort* qkv  = (ushort*)d_ws;                 // M x 384 bf16
    ushort* Wp_t = qkv + (size_t)M * 384;         // 128 x 128 bf16

    qkv_gemm_fused_kernel<<<dim3(128, 4), 256, 0, stream>>>(
        x, w_qkv, b_qkv, w_proj, qkv, Wp_t);

    natten_proj_kernel<<<256, 512, 0, stream>>>(
        qkv, rpb, Wp_t, b_proj, out);
}